// Round 3
// baseline (791.016 us; speedup 1.0000x reference)
//
#include <hip/hip_runtime.h>

typedef __bf16 bf16x8 __attribute__((ext_vector_type(8)));
typedef __bf16 bf16x4 __attribute__((ext_vector_type(4)));
typedef float  f32x4  __attribute__((ext_vector_type(4)));

#define NTOK  49
#define CDIM  128
#define LOG2E 1.4426950408889634f
#define QK2   (0.17677669529663687f * LOG2E)   // 1/sqrt(32) * log2(e)

// workspace offsets (bytes)
#define WQKV_OFF  0          // 384*128 bf16 = 98304  (q/k sections chan-permuted)
#define WPROJ_OFF 98304      // 128*128 bf16 = 32768
#define BIASB_OFF 131072     // [4][64][64] bf16 (log2e-scaled bias) = 32768
#define MASKB_OFF 163840     // [64][64][64] bf16 (log2e-scaled mask; j>=49 -> -1e30) = 524288

// Uniform LDS XOR swizzle on 8-element (16 B) granules within 64-col groups.
__device__ __forceinline__ int swz(int row, int col) {
    return (col & ~63) | ((((col >> 3) ^ row) & 7) << 3) | (col & 7);
}

__global__ void prep_kernel(const float* __restrict__ qkv_w,
                            const float* __restrict__ proj_w,
                            const float* __restrict__ bias_table,
                            const int*   __restrict__ rel_index,
                            const float* __restrict__ mask,
                            __bf16* __restrict__ wqkv,
                            __bf16* __restrict__ wproj,
                            __bf16* __restrict__ biasb,
                            __bf16* __restrict__ maskb) {
    int t = blockIdx.x * 256 + threadIdx.x;      // 0..65535 (256 blocks)
    if (t < 384 * 128) {
        // q/k sections stored chan-PERMUTED so that winattn's phase-1 MFMA
        // output slots (quad,r) hold chan quad*8 + half*4 + r directly:
        // permuted row r' = h*32 + half*16 + l16  <- orig chan
        //   h*32 + (l16>>2)*8 + half*4 + (l16&3).
        int row = t >> 7, c = t & 127;
        int orow;
        if (row < 256) {
            int sec = row >> 7;            // 0 = q, 1 = k
            int h   = (row & 127) >> 5;
            int w5  = row & 31;
            int half = w5 >> 4, l = w5 & 15;
            orow = sec * 128 + h * 32 + ((l >> 2) << 3) + half * 4 + (l & 3);
        } else {
            orow = row;                    // v natural
        }
        wqkv[t] = (__bf16)qkv_w[orow * 128 + c];
    }
    if (t < 128 * 128) wproj[t] = (__bf16)proj_w[t];
    if (t < 4096) {                               // biasb[h][i][j], 4 j per thread
        int base = t * 4;
        int h = base >> 12, i = (base >> 6) & 63, j0 = base & 63;
        bf16x4 v;
        #pragma unroll
        for (int r = 0; r < 4; ++r) {
            int j = j0 + r;
            float f = 0.f;
            if (i < NTOK && j < NTOK) f = bias_table[rel_index[i*49 + j] * 4 + h] * LOG2E;
            v[r] = (__bf16)f;
        }
        *(bf16x4*)&biasb[base] = v;
    }
    {                                             // maskb[wm][i][j], 4 j per thread
        int base = t * 4;
        int wm = base >> 12, i = (base >> 6) & 63, j0 = base & 63;
        bf16x4 v;
        #pragma unroll
        for (int r = 0; r < 4; ++r) {
            int j = j0 + r;
            float f;
            if (j >= NTOK)      f = -1e30f;       // masked key -> exp2 = 0
            else if (i < NTOK)  f = mask[wm*2401 + i*49 + j] * LOG2E;
            else                f = 0.f;
            v[r] = (__bf16)f;
        }
        *(bf16x4*)&maskb[base] = v;
    }
}

__launch_bounds__(256, 4)
__global__ void winattn_kernel(const float* __restrict__ x,
                               const float* __restrict__ qkv_b,
                               const float* __restrict__ proj_b,
                               const __bf16* __restrict__ wqkv,
                               const __bf16* __restrict__ wproj,
                               const __bf16* __restrict__ biasb,
                               const __bf16* __restrict__ maskb,
                               float* __restrict__ out) {
    // lds_xv: x [64][128] -> vt [128][64] (token-permuted cols)   16 KB
    // lds_o : O [64][128]                                         16 KB
    __shared__ __bf16 lds_xv[64 * 128];
    __shared__ __bf16 lds_o [64 * 128];

    const int tid  = threadIdx.x;
    const int w    = blockIdx.x;
    const int h    = tid >> 6;            // wave = head
    const int lane = tid & 63;
    const int quad = lane >> 4;
    const int l16  = lane & 15;

    // ---------------- phase 0: x (fp32) -> lds_xv (bf16), rows>=49 zeroed ---
    {
        int row = tid >> 2;           // 0..63
        int c0  = (tid & 3) * 32;     // 0,32,64,96
        __align__(16) __bf16 tmp[32];
        if (row < NTOK) {
            const float4* src = (const float4*)(x + ((size_t)w * NTOK + row) * CDIM + c0);
            #pragma unroll
            for (int i = 0; i < 8; ++i) {
                float4 f = src[i];
                tmp[i*4+0] = (__bf16)f.x; tmp[i*4+1] = (__bf16)f.y;
                tmp[i*4+2] = (__bf16)f.z; tmp[i*4+3] = (__bf16)f.w;
            }
        } else {
            #pragma unroll
            for (int i = 0; i < 32; ++i) tmp[i] = (__bf16)0.0f;
        }
        #pragma unroll
        for (int i = 0; i < 4; ++i)
            *(bf16x8*)&lds_xv[row * 128 + swz(row, c0 + i*8)] = *(bf16x8*)&tmp[i*8];
    }
    __syncthreads();   // B1: x visible

    // ---------------- phase 1: qkv = x @ Wqkv^T + b (all in registers) -----
    // Wave h computes ONLY head h's q,k (chans h*32..+31) and v-tiles 2h,2h+1.
    // Permuted W rows make output slot (quad,r) of half T = chan quad*8+T*4+r,
    // so packing elem e = T*4+r yields exactly the phase-2 fragment layout:
    // elem e <-> chan quad*8+e, token = l16 (per mt tile).
    bf16x8 qf[4], kf[4];     // [mt]: elem e = half*4+r
    bf16x4 vreg[2][4];       // [half][mt]: V[tok=mt*16+quad*4+r][chan=h*32+half*16+l16]
    #pragma unroll
    for (int half = 0; half < 2; ++half) {
        f32x4 aq[4], ak[4], av[4];
        #pragma unroll
        for (int m = 0; m < 4; ++m) {
            aq[m] = (f32x4){0.f,0.f,0.f,0.f};
            ak[m] = (f32x4){0.f,0.f,0.f,0.f};
            av[m] = (f32x4){0.f,0.f,0.f,0.f};
        }
        #pragma unroll
        for (int kt = 0; kt < 4; ++kt) {
            bf16x8 xf[4];
            #pragma unroll
            for (int mt = 0; mt < 4; ++mt) {
                int rr = mt*16 + l16;
                xf[mt] = *(bf16x8*)&lds_xv[rr * 128 + swz(rr, kt*32 + quad*8)];
            }
            size_t ro = (size_t)(h*32 + half*16 + l16) * CDIM + kt*32 + quad*8;
            bf16x8 wq = *(const bf16x8*)(wqkv + ro);
            bf16x8 wk = *(const bf16x8*)(wqkv + 128*CDIM + ro);
            bf16x8 wv = *(const bf16x8*)(wqkv + 256*CDIM + ro);
            #pragma unroll
            for (int mt = 0; mt < 4; ++mt) {
                aq[mt] = __builtin_amdgcn_mfma_f32_16x16x32_bf16(wq, xf[mt], aq[mt], 0, 0, 0); // D[chan][tok]
                ak[mt] = __builtin_amdgcn_mfma_f32_16x16x32_bf16(wk, xf[mt], ak[mt], 0, 0, 0); // D[chan][tok]
                av[mt] = __builtin_amdgcn_mfma_f32_16x16x32_bf16(xf[mt], wv, av[mt], 0, 0, 0); // D[tok][chan]
            }
        }
        float4 bq4 = *(const float4*)&qkv_b[      h*32 + quad*8 + half*4];
        float4 bk4 = *(const float4*)&qkv_b[128 + h*32 + quad*8 + half*4];
        float  bv1 = qkv_b[256 + h*32 + half*16 + l16];
        #pragma unroll
        for (int mt = 0; mt < 4; ++mt) {
            #pragma unroll
            for (int r = 0; r < 4; ++r) {
                qf[mt][half*4+r] = (__bf16)((aq[mt][r] + ((const float*)&bq4)[r]) * QK2);
                kf[mt][half*4+r] = (__bf16)( ak[mt][r] + ((const float*)&bk4)[r]);
            }
            bf16x4 vv;
            #pragma unroll
            for (int r = 0; r < 4; ++r) vv[r] = (__bf16)(av[mt][r] + bv1);
            vreg[half][mt] = vv;
        }
    }
    __syncthreads();   // B2: all x reads done -> lds_xv reusable as vt

    // vt[chan][phi(tok)]: token-permuted cols so phase-3's b128 read at
    // col kt*32+quad*8 yields elem e <-> tok kt*32+(e>>2)*16+quad*4+(e&3),
    // matching P's in-lane k-slot layout. Wave-private (own head's chans).
    #pragma unroll
    for (int half = 0; half < 2; ++half) {
        int vc = h*32 + half*16 + l16;
        #pragma unroll
        for (int mt = 0; mt < 4; ++mt) {
            int col = (mt >> 1)*32 + quad*8 + (mt & 1)*4;
            *(bf16x4*)&lds_xv[vc * 64 + swz(vc, col)] = vreg[half][mt];
        }
    }

    // ---------------- phase 2: S^T = k q^T; softmax fully in registers -----
    bf16x8 pf[4][2];   // [mtq][kt]: elem e = (ntk&1)*4+r, ktok = kt*32+(e>>2)*16+quad*4+(e&3)
    float inv[4];
    {
        const __bf16* bb = biasb + h * 4096;
        const __bf16* mb = maskb + (size_t)(w & 63) * 4096;
        #pragma unroll
        for (int mtq = 0; mtq < 4; ++mtq) {
            f32x4 s2[4];
            #pragma unroll
            for (int ntk = 0; ntk < 4; ++ntk) {
                f32x4 z = (f32x4){0.f,0.f,0.f,0.f};
                s2[ntk] = __builtin_amdgcn_mfma_f32_16x16x32_bf16(kf[ntk], qf[mtq], z, 0, 0, 0);
            }
            int i = mtq*16 + l16;                // qtok (lane-resident)
            float e[4][4], sum = 0.f;
            #pragma unroll
            for (int ntk = 0; ntk < 4; ++ntk) {
                int j0 = ntk*16 + quad*4;        // ktok base
                bf16x4 b4 = *(const bf16x4*)&bb[i*64 + j0];
                bf16x4 m4 = *(const bf16x4*)&mb[i*64 + j0];
                #pragma unroll
                for (int r = 0; r < 4; ++r) {
                    float t = s2[ntk][r] + (float)b4[r] + (float)m4[r];
                    e[ntk][r] = __builtin_amdgcn_exp2f(t);
                    sum += e[ntk][r];
                }
            }
            sum += __shfl_xor(sum, 16, 64);
            sum += __shfl_xor(sum, 32, 64);
            inv[mtq] = __builtin_amdgcn_rcpf(sum);
            #pragma unroll
            for (int kt = 0; kt < 2; ++kt) {
                bf16x8 p8;
                #pragma unroll
                for (int b = 0; b < 2; ++b)
                    #pragma unroll
                    for (int r = 0; r < 4; ++r)
                        p8[b*4+r] = (__bf16)e[2*kt+b][r];
                pf[mtq][kt] = p8;
            }
        }
    }

    // ---------------- phase 3: O^T = V^T P^T (vt wave-private, no barrier) -
    {
        bf16x8 vf[2][2];
        #pragma unroll
        for (int nv = 0; nv < 2; ++nv)
            #pragma unroll
            for (int kt = 0; kt < 2; ++kt) {
                int vr = h*32 + nv*16 + l16;     // chan
                vf[nv][kt] = *(bf16x8*)&lds_xv[vr*64 + swz(vr, kt*32 + quad*8)];
            }
        f32x4 oacc[2][4];  // [nv][mtq]: D[chan][qtok]
        #pragma unroll
        for (int a = 0; a < 2; ++a)
            #pragma unroll
            for (int b = 0; b < 4; ++b) oacc[a][b] = (f32x4){0.f,0.f,0.f,0.f};
        #pragma unroll
        for (int mtq = 0; mtq < 4; ++mtq)
            #pragma unroll
            for (int kt = 0; kt < 2; ++kt)
                #pragma unroll
                for (int nv = 0; nv < 2; ++nv)
                    oacc[nv][mtq] = __builtin_amdgcn_mfma_f32_16x16x32_bf16(
                        vf[nv][kt], pf[mtq][kt], oacc[nv][mtq], 0, 0, 0);

        // normalize, store O_rm[qtok][chan] into lds_o
        #pragma unroll
        for (int nv = 0; nv < 2; ++nv)
            #pragma unroll
            for (int mtq = 0; mtq < 4; ++mtq) {
                int row = mtq*16 + l16;          // qtok
                bf16x4 ov;
                #pragma unroll
                for (int r = 0; r < 4; ++r) ov[r] = (__bf16)(oacc[nv][mtq][r] * inv[mtq]);
                *(bf16x4*)&lds_o[row*128 + swz(row, h*32 + nv*16 + quad*4)] = ov;
            }
    }
    __syncthreads();   // B3: O visible

    // ---------------- phase 4: out^T = Wproj O^T ---------------------------
    #pragma unroll
    for (int ntl = 0; ntl < 2; ++ntl) {
        int oc = (h*2 + ntl) * 16;               // out-chan tile base
        f32x4 acc[4];
        #pragma unroll
        for (int a = 0; a < 4; ++a) acc[a] = (f32x4){0.f,0.f,0.f,0.f};
        #pragma unroll
        for (int kt = 0; kt < 4; ++kt) {
            bf16x8 wf = *(const bf16x8*)(wproj + (size_t)(oc + l16) * CDIM + kt*32 + quad*8);
            #pragma unroll
            for (int mt = 0; mt < 4; ++mt) {
                int rr = mt*16 + l16;
                bf16x8 of = *(bf16x8*)&lds_o[rr*128 + swz(rr, kt*32 + quad*8)];
                acc[mt] = __builtin_amdgcn_mfma_f32_16x16x32_bf16(wf, of, acc[mt], 0, 0, 0); // D[ochan][tok]
            }
        }
        float4 pb4 = *(const float4*)&proj_b[oc + quad*4];
        #pragma unroll
        for (int mt = 0; mt < 4; ++mt) {
            int tok = mt*16 + l16;
            if (tok < NTOK) {
                float4 o4;
                o4.x = acc[mt][0] + pb4.x;
                o4.y = acc[mt][1] + pb4.y;
                o4.z = acc[mt][2] + pb4.z;
                o4.w = acc[mt][3] + pb4.w;
                *(float4*)&out[((size_t)w * NTOK + tok) * CDIM + oc + quad*4] = o4;
            }
        }
    }
}

extern "C" void kernel_launch(void* const* d_in, const int* in_sizes, int n_in,
                              void* d_out, int out_size, void* d_ws, size_t ws_size,
                              hipStream_t stream) {
    const float* x          = (const float*)d_in[0];
    const float* mask       = (const float*)d_in[1];
    const float* qkv_w      = (const float*)d_in[2];
    const float* qkv_b      = (const float*)d_in[3];
    const float* proj_w     = (const float*)d_in[4];
    const float* proj_b     = (const float*)d_in[5];
    const float* bias_table = (const float*)d_in[6];
    const int*   rel_index  = (const int*)d_in[7];

    __bf16* wqkv  = (__bf16*)((char*)d_ws + WQKV_OFF);
    __bf16* wproj = (__bf16*)((char*)d_ws + WPROJ_OFF);
    __bf16* biasb = (__bf16*)((char*)d_ws + BIASB_OFF);
    __bf16* maskb = (__bf16*)((char*)d_ws + MASKB_OFF);

    int nwb = in_sizes[0] / (NTOK * CDIM);   // 8192

    prep_kernel<<<256, 256, 0, stream>>>(qkv_w, proj_w, bias_table, rel_index, mask,
                                         wqkv, wproj, biasb, maskb);
    winattn_kernel<<<nwb, 256, 0, stream>>>(x, qkv_b, proj_b,
                                            wqkv, wproj, biasb, maskb, (float*)d_out);
}

// Round 6
// 563.711 us; speedup vs baseline: 1.4032x; 1.4032x over previous
//
// v5: identical semantics to R4 submission; version bump to invalidate any
// source-hash-keyed build cache after two container-level bench failures.
#include <hip/hip_runtime.h>

typedef __bf16 bf16x8 __attribute__((ext_vector_type(8)));
typedef __bf16 bf16x4 __attribute__((ext_vector_type(4)));
typedef float  f32x4  __attribute__((ext_vector_type(4)));

#define NTOK  49
#define CDIM  128
#define LOG2E 1.4426950408889634f
#define QK2   (0.17677669529663687f * LOG2E)   // 1/sqrt(32) * log2(e)

// workspace offsets (bytes)
#define WQKV_OFF  0          // 384*128 bf16 = 98304  (q/k sections chan-permuted)
#define WPROJ_OFF 98304      // 128*128 bf16 = 32768
#define BIASB_OFF 131072     // [4][64][64] bf16 (log2e-scaled bias) = 32768
#define MASKB_OFF 163840     // [64][64][64] bf16 (log2e-scaled mask; j>=49 -> -1e30) = 524288

// Uniform LDS XOR swizzle on 8-element (16 B) granules within 64-col groups.
__device__ __forceinline__ int swz(int row, int col) {
    return (col & ~63) | ((((col >> 3) ^ row) & 7) << 3) | (col & 7);
}

__global__ void prep_kernel(const float* __restrict__ qkv_w,
                            const float* __restrict__ proj_w,
                            const float* __restrict__ bias_table,
                            const int*   __restrict__ rel_index,
                            const float* __restrict__ mask,
                            __bf16* __restrict__ wqkv,
                            __bf16* __restrict__ wproj,
                            __bf16* __restrict__ biasb,
                            __bf16* __restrict__ maskb) {
    int t = blockIdx.x * 256 + threadIdx.x;      // 0..65535 (256 blocks)
    if (t < 384 * 128) {
        // q/k sections stored chan-PERMUTED so that winattn's phase-1 MFMA
        // output slots (quad,r) hold chan quad*8 + half*4 + r directly:
        // permuted row r' = h*32 + half*16 + l16  <- orig chan
        //   h*32 + (l16>>2)*8 + half*4 + (l16&3).
        int row = t >> 7, c = t & 127;
        int orow;
        if (row < 256) {
            int sec = row >> 7;            // 0 = q, 1 = k
            int h   = (row & 127) >> 5;
            int w5  = row & 31;
            int half = w5 >> 4, l = w5 & 15;
            orow = sec * 128 + h * 32 + ((l >> 2) << 3) + half * 4 + (l & 3);
        } else {
            orow = row;                    // v natural
        }
        wqkv[t] = (__bf16)qkv_w[orow * 128 + c];
    }
    if (t < 128 * 128) wproj[t] = (__bf16)proj_w[t];
    if (t < 4096) {                               // biasb[h][i][j], 4 j per thread
        int base = t * 4;
        int h = base >> 12, i = (base >> 6) & 63, j0 = base & 63;
        bf16x4 v;
        #pragma unroll
        for (int r = 0; r < 4; ++r) {
            int j = j0 + r;
            float f = 0.f;
            if (i < NTOK && j < NTOK) f = bias_table[rel_index[i*49 + j] * 4 + h] * LOG2E;
            v[r] = (__bf16)f;
        }
        *(bf16x4*)&biasb[base] = v;
    }
    {                                             // maskb[wm][i][j], 4 j per thread
        int base = t * 4;
        int wm = base >> 12, i = (base >> 6) & 63, j0 = base & 63;
        bf16x4 v;
        #pragma unroll
        for (int r = 0; r < 4; ++r) {
            int j = j0 + r;
            float f;
            if (j >= NTOK)      f = -1e30f;       // masked key -> exp2 = 0
            else if (i < NTOK)  f = mask[wm*2401 + i*49 + j] * LOG2E;
            else                f = 0.f;
            v[r] = (__bf16)f;
        }
        *(bf16x4*)&maskb[base] = v;
    }
}

// (256,3): VGPR cap 170 -> allocator never spills (R3 lesson: cap 128 forced
// 64 arch VGPRs + scratch, 5x HBM traffic). Actual use ~110-125 -> HW gives
// 4 waves/SIMD; LDS 32KB allows 5 blocks/CU.
__launch_bounds__(256, 3)
__global__ void winattn_kernel(const float* __restrict__ x,
                               const float* __restrict__ qkv_b,
                               const float* __restrict__ proj_b,
                               const __bf16* __restrict__ wqkv,
                               const __bf16* __restrict__ wproj,
                               const __bf16* __restrict__ biasb,
                               const __bf16* __restrict__ maskb,
                               float* __restrict__ out) {
    // lds_xv: x [64][128] -> vt [128][64] (token-permuted cols)   16 KB
    // lds_o : O [64][128]                                         16 KB
    __shared__ __bf16 lds_xv[64 * 128];
    __shared__ __bf16 lds_o [64 * 128];

    const int tid  = threadIdx.x;
    const int w    = blockIdx.x;
    const int h    = tid >> 6;            // wave = head
    const int lane = tid & 63;
    const int quad = lane >> 4;
    const int l16  = lane & 15;

    // ---------------- phase 0: x (fp32) -> lds_xv (bf16), rows>=49 zeroed ---
    {
        int row = tid >> 2;           // 0..63
        int c0  = (tid & 3) * 32;     // 0,32,64,96
        __align__(16) __bf16 tmp[32];
        if (row < NTOK) {
            const float4* src = (const float4*)(x + ((size_t)w * NTOK + row) * CDIM + c0);
            #pragma unroll
            for (int i = 0; i < 8; ++i) {
                float4 f = src[i];
                tmp[i*4+0] = (__bf16)f.x; tmp[i*4+1] = (__bf16)f.y;
                tmp[i*4+2] = (__bf16)f.z; tmp[i*4+3] = (__bf16)f.w;
            }
        } else {
            #pragma unroll
            for (int i = 0; i < 32; ++i) tmp[i] = (__bf16)0.0f;
        }
        #pragma unroll
        for (int i = 0; i < 4; ++i)
            *(bf16x8*)&lds_xv[row * 128 + swz(row, c0 + i*8)] = *(bf16x8*)&tmp[i*8];
    }
    __syncthreads();   // B1: x visible

    // ---------------- phase 1: qkv = x @ Wqkv^T + b (all in registers) -----
    // Wave h computes ONLY head h's q,k (chans h*32..+31) and v-tiles 2h,2h+1.
    // Split into pass A (q,k: 32 acc regs) and pass B (v: 16 acc regs) to
    // keep peak VGPR pressure ~110 (single fused pass was 140 -> R3 spills).
    bf16x8 qf[4], kf[4];     // [mt]: elem e = half*4+r <-> chan quad*8+e, tok l16
    bf16x4 vreg[2][4];       // [half][mt]: V[tok=mt*16+quad*4+r][chan=h*32+half*16+l16]

    // ---- pass A: q,k ----
    #pragma unroll
    for (int half = 0; half < 2; ++half) {
        f32x4 aq[4], ak[4];
        #pragma unroll
        for (int m = 0; m < 4; ++m) {
            aq[m] = (f32x4){0.f,0.f,0.f,0.f};
            ak[m] = (f32x4){0.f,0.f,0.f,0.f};
        }
        #pragma unroll
        for (int kt = 0; kt < 4; ++kt) {
            bf16x8 xf[4];
            #pragma unroll
            for (int mt = 0; mt < 4; ++mt) {
                int rr = mt*16 + l16;
                xf[mt] = *(bf16x8*)&lds_xv[rr * 128 + swz(rr, kt*32 + quad*8)];
            }
            size_t ro = (size_t)(h*32 + half*16 + l16) * CDIM + kt*32 + quad*8;
            bf16x8 wq = *(const bf16x8*)(wqkv + ro);
            bf16x8 wk = *(const bf16x8*)(wqkv + 128*CDIM + ro);
            #pragma unroll
            for (int mt = 0; mt < 4; ++mt) {
                aq[mt] = __builtin_amdgcn_mfma_f32_16x16x32_bf16(wq, xf[mt], aq[mt], 0, 0, 0); // D[chan][tok]
                ak[mt] = __builtin_amdgcn_mfma_f32_16x16x32_bf16(wk, xf[mt], ak[mt], 0, 0, 0); // D[chan][tok]
            }
        }
        float4 bq4 = *(const float4*)&qkv_b[      h*32 + quad*8 + half*4];
        float4 bk4 = *(const float4*)&qkv_b[128 + h*32 + quad*8 + half*4];
        #pragma unroll
        for (int mt = 0; mt < 4; ++mt)
            #pragma unroll
            for (int r = 0; r < 4; ++r) {
                qf[mt][half*4+r] = (__bf16)((aq[mt][r] + ((const float*)&bq4)[r]) * QK2);
                kf[mt][half*4+r] = (__bf16)( ak[mt][r] + ((const float*)&bk4)[r]);
            }
    }

    // ---- pass B: v ----
    #pragma unroll
    for (int half = 0; half < 2; ++half) {
        f32x4 av[4];
        #pragma unroll
        for (int m = 0; m < 4; ++m) av[m] = (f32x4){0.f,0.f,0.f,0.f};
        #pragma unroll
        for (int kt = 0; kt < 4; ++kt) {
            bf16x8 xf[4];
            #pragma unroll
            for (int mt = 0; mt < 4; ++mt) {
                int rr = mt*16 + l16;
                xf[mt] = *(bf16x8*)&lds_xv[rr * 128 + swz(rr, kt*32 + quad*8)];
            }
            bf16x8 wv = *(const bf16x8*)(wqkv + 256*CDIM
                          + (size_t)(h*32 + half*16 + l16) * CDIM + kt*32 + quad*8);
            #pragma unroll
            for (int mt = 0; mt < 4; ++mt)
                av[mt] = __builtin_amdgcn_mfma_f32_16x16x32_bf16(xf[mt], wv, av[mt], 0, 0, 0); // D[tok][chan]
        }
        float bv1 = qkv_b[256 + h*32 + half*16 + l16];
        #pragma unroll
        for (int mt = 0; mt < 4; ++mt) {
            bf16x4 vv;
            #pragma unroll
            for (int r = 0; r < 4; ++r) vv[r] = (__bf16)(av[mt][r] + bv1);
            vreg[half][mt] = vv;
        }
    }
    __syncthreads();   // B2: all x reads done -> lds_xv reusable as vt

    // vt[chan][phi(tok)]: token-permuted cols so phase-3's b128 read at
    // col kt*32+quad*8 yields elem e <-> tok kt*32+(e>>2)*16+quad*4+(e&3),
    // matching P's in-lane k-slot layout. Wave-private (own head's chans).
    #pragma unroll
    for (int half = 0; half < 2; ++half) {
        int vc = h*32 + half*16 + l16;
        #pragma unroll
        for (int mt = 0; mt < 4; ++mt) {
            int col = (mt >> 1)*32 + quad*8 + (mt & 1)*4;
            *(bf16x4*)&lds_xv[vc * 64 + swz(vc, col)] = vreg[half][mt];
        }
    }

    // ---------------- phase 2: S^T = k q^T; softmax fully in registers -----
    bf16x8 pf[4][2];   // [mtq][kt]: elem e = (ntk&1)*4+r, ktok = kt*32+(e>>2)*16+quad*4+(e&3)
    float inv[4];
    {
        const __bf16* bb = biasb + h * 4096;
        const __bf16* mb = maskb + (size_t)(w & 63) * 4096;
        #pragma unroll
        for (int mtq = 0; mtq < 4; ++mtq) {
            f32x4 s2[4];
            #pragma unroll
            for (int ntk = 0; ntk < 4; ++ntk) {
                f32x4 z = (f32x4){0.f,0.f,0.f,0.f};
                s2[ntk] = __builtin_amdgcn_mfma_f32_16x16x32_bf16(kf[ntk], qf[mtq], z, 0, 0, 0);
            }
            int i = mtq*16 + l16;                // qtok (lane-resident)
            float e[4][4], sum = 0.f;
            #pragma unroll
            for (int ntk = 0; ntk < 4; ++ntk) {
                int j0 = ntk*16 + quad*4;        // ktok base
                bf16x4 b4 = *(const bf16x4*)&bb[i*64 + j0];
                bf16x4 m4 = *(const bf16x4*)&mb[i*64 + j0];
                #pragma unroll
                for (int r = 0; r < 4; ++r) {
                    float t = s2[ntk][r] + (float)b4[r] + (float)m4[r];
                    e[ntk][r] = __builtin_amdgcn_exp2f(t);
                    sum += e[ntk][r];
                }
            }
            sum += __shfl_xor(sum, 16, 64);
            sum += __shfl_xor(sum, 32, 64);
            inv[mtq] = __builtin_amdgcn_rcpf(sum);
            #pragma unroll
            for (int kt = 0; kt < 2; ++kt) {
                bf16x8 p8;
                #pragma unroll
                for (int b = 0; b < 2; ++b)
                    #pragma unroll
                    for (int r = 0; r < 4; ++r)
                        p8[b*4+r] = (__bf16)e[2*kt+b][r];
                pf[mtq][kt] = p8;
            }
        }
    }

    // ---------------- phase 3: O^T = V^T P^T (vt wave-private, no barrier) -
    {
        bf16x8 vf[2][2];
        #pragma unroll
        for (int nv = 0; nv < 2; ++nv)
            #pragma unroll
            for (int kt = 0; kt < 2; ++kt) {
                int vr = h*32 + nv*16 + l16;     // chan
                vf[nv][kt] = *(bf16x8*)&lds_xv[vr*64 + swz(vr, kt*32 + quad*8)];
            }
        f32x4 oacc[2][4];  // [nv][mtq]: D[chan][qtok]
        #pragma unroll
        for (int a = 0; a < 2; ++a)
            #pragma unroll
            for (int b = 0; b < 4; ++b) oacc[a][b] = (f32x4){0.f,0.f,0.f,0.f};
        #pragma unroll
        for (int mtq = 0; mtq < 4; ++mtq)
            #pragma unroll
            for (int kt = 0; kt < 2; ++kt)
                #pragma unroll
                for (int nv = 0; nv < 2; ++nv)
                    oacc[nv][mtq] = __builtin_amdgcn_mfma_f32_16x16x32_bf16(
                        vf[nv][kt], pf[mtq][kt], oacc[nv][mtq], 0, 0, 0);

        // normalize, store O_rm[qtok][chan] into lds_o
        #pragma unroll
        for (int nv = 0; nv < 2; ++nv)
            #pragma unroll
            for (int mtq = 0; mtq < 4; ++mtq) {
                int row = mtq*16 + l16;          // qtok
                bf16x4 ov;
                #pragma unroll
                for (int r = 0; r < 4; ++r) ov[r] = (__bf16)(oacc[nv][mtq][r] * inv[mtq]);
                *(bf16x4*)&lds_o[row*128 + swz(row, h*32 + nv*16 + quad*4)] = ov;
            }
    }
    __syncthreads();   // B3: O visible

    // ---------------- phase 4: out^T = Wproj O^T ---------------------------
    #pragma unroll
    for (int ntl = 0; ntl < 2; ++ntl) {
        int oc = (h*2 + ntl) * 16;               // out-chan tile base
        f32x4 acc[4];
        #pragma unroll
        for (int a = 0; a < 4; ++a) acc[a] = (f32x4){0.f,0.f,0.f,0.f};
        #pragma unroll
        for (int kt = 0; kt < 4; ++kt) {
            bf16x8 wf = *(const bf16x8*)(wproj + (size_t)(oc + l16) * CDIM + kt*32 + quad*8);
            #pragma unroll
            for (int mt = 0; mt < 4; ++mt) {
                int rr = mt*16 + l16;
                bf16x8 of = *(bf16x8*)&lds_o[rr*128 + swz(rr, kt*32 + quad*8)];
                acc[mt] = __builtin_amdgcn_mfma_f32_16x16x32_bf16(wf, of, acc[mt], 0, 0, 0); // D[ochan][tok]
            }
        }
        float4 pb4 = *(const float4*)&proj_b[oc + quad*4];
        #pragma unroll
        for (int mt = 0; mt < 4; ++mt) {
            int tok = mt*16 + l16;
            if (tok < NTOK) {
                float4 o4;
                o4.x = acc[mt][0] + pb4.x;
                o4.y = acc[mt][1] + pb4.y;
                o4.z = acc[mt][2] + pb4.z;
                o4.w = acc[mt][3] + pb4.w;
                *(float4*)&out[((size_t)w * NTOK + tok) * CDIM + oc + quad*4] = o4;
            }
        }
    }
}

extern "C" void kernel_launch(void* const* d_in, const int* in_sizes, int n_in,
                              void* d_out, int out_size, void* d_ws, size_t ws_size,
                              hipStream_t stream) {
    const float* x          = (const float*)d_in[0];
    const float* mask       = (const float*)d_in[1];
    const float* qkv_w      = (const float*)d_in[2];
    const float* qkv_b      = (const float*)d_in[3];
    const float* proj_w     = (const float*)d_in[4];
    const float* proj_b     = (const float*)d_in[5];
    const float* bias_table = (const float*)d_in[6];
    const int*   rel_index  = (const int*)d_in[7];

    __bf16* wqkv  = (__bf16*)((char*)d_ws + WQKV_OFF);
    __bf16* wproj = (__bf16*)((char*)d_ws + WPROJ_OFF);
    __bf16* biasb = (__bf16*)((char*)d_ws + BIASB_OFF);
    __bf16* maskb = (__bf16*)((char*)d_ws + MASKB_OFF);

    int nwb = in_sizes[0] / (NTOK * CDIM);   // 8192

    prep_kernel<<<256, 256, 0, stream>>>(qkv_w, proj_w, bias_table, rel_index, mask,
                                         wqkv, wproj, biasb, maskb);
    winattn_kernel<<<nwb, 256, 0, stream>>>(x, qkv_b, proj_b,
                                            wqkv, wproj, biasb, maskb, (float*)d_out);
}